// Round 1
// baseline (707.063 us; speedup 1.0000x reference)
//
#include <hip/hip_runtime.h>
#include <hip/hip_bf16.h>

#define B_ 4
#define N_ 4096
#define D_ 1024
#define H_ 16
#define E_ 256
#define HD_ 64

typedef __attribute__((ext_vector_type(8))) short bf16x8;
typedef __attribute__((ext_vector_type(4))) float floatx4;

__device__ inline short f2bf(float f) {
  __hip_bfloat16 h = __float2bfloat16(f);
  short s;
  __builtin_memcpy(&s, &h, 2);
  return s;
}

// ---------------- transpose + cast fp32 -> bf16 ----------------
// src [R, C] fp32 row-major -> dstT [C, R] bf16 row-major
__global__ void transpose_cast_kernel(const float* __restrict__ src,
                                      short* __restrict__ dstT,
                                      int R, int C) {
  __shared__ float tile[32][33];
  int c0 = blockIdx.x * 32;
  int r0 = blockIdx.y * 32;
  int tx = threadIdx.x;   // 0..31
  int ty = threadIdx.y;   // 0..7
#pragma unroll
  for (int i = 0; i < 4; ++i) {
    int r = ty * 4 + i;
    tile[r][tx] = src[(size_t)(r0 + r) * C + (c0 + tx)];
  }
  __syncthreads();
#pragma unroll
  for (int i = 0; i < 4; ++i) {
    int c = ty * 4 + i;
    dstT[(size_t)(c0 + c) * R + (r0 + tx)] = f2bf(tile[tx][c]);
  }
}

// ---------------- generic C = A * Bt^T bf16 MFMA GEMM ----------------
// A  [M, K]  (bf16, or fp32 if AF32 — cast on the fly)
// Bt [Nc, K] bf16 (i.e. B transposed, contiguous in K)
// C  [M, Nc] bf16  (or C^T [Nc, M] if STORE_T)
// block = 256 threads = 4 waves, block tile 64x64, wave tile 32x32 (2x2 MFMA)
template <bool AF32, bool STORE_T>
__global__ __launch_bounds__(256) void gemm_bt_kernel(
    const void* __restrict__ Av, const short* __restrict__ Btv,
    short* __restrict__ Cv, int M, int Nc, int K,
    long sA, long sB, long sC) {
  int tid = threadIdx.x;
  int w = tid >> 6;
  int lane = tid & 63;
  int l16 = lane & 15;
  int quad = lane >> 4;
  int m_base = blockIdx.x * 64 + (w >> 1) * 32;
  int n_base = blockIdx.y * 64 + (w & 1) * 32;

  const float* Af = AF32 ? ((const float*)Av + (size_t)blockIdx.z * sA) : nullptr;
  const short* Ab = AF32 ? nullptr : ((const short*)Av + (size_t)blockIdx.z * sA);
  const short* Bt = Btv + (size_t)blockIdx.z * sB;
  short* C = Cv + (size_t)blockIdx.z * sC;

  floatx4 acc[2][2];
#pragma unroll
  for (int i = 0; i < 2; ++i)
#pragma unroll
    for (int j = 0; j < 2; ++j) acc[i][j] = (floatx4){0.f, 0.f, 0.f, 0.f};

  for (int k = 0; k < K; k += 32) {
    bf16x8 a[2], b[2];
#pragma unroll
    for (int mt = 0; mt < 2; ++mt) {
      size_t row = (size_t)(m_base + mt * 16 + l16);
      if constexpr (AF32) {
        const float* p = Af + row * K + k + quad * 8;
        bf16x8 v;
#pragma unroll
        for (int j = 0; j < 8; ++j) v[j] = f2bf(p[j]);
        a[mt] = v;
      } else {
        a[mt] = *(const bf16x8*)(Ab + row * K + k + quad * 8);
      }
    }
#pragma unroll
    for (int nt = 0; nt < 2; ++nt) {
      size_t col = (size_t)(n_base + nt * 16 + l16);
      b[nt] = *(const bf16x8*)(Bt + col * K + k + quad * 8);
    }
#pragma unroll
    for (int mt = 0; mt < 2; ++mt)
#pragma unroll
      for (int nt = 0; nt < 2; ++nt)
        acc[mt][nt] = __builtin_amdgcn_mfma_f32_16x16x32_bf16(a[mt], b[nt], acc[mt][nt], 0, 0, 0);
  }

#pragma unroll
  for (int mt = 0; mt < 2; ++mt)
#pragma unroll
    for (int nt = 0; nt < 2; ++nt)
#pragma unroll
      for (int r = 0; r < 4; ++r) {
        size_t row = (size_t)(m_base + mt * 16 + quad * 4 + r);
        size_t col = (size_t)(n_base + nt * 16 + l16);
        short v = f2bf(acc[mt][nt][r]);
        if constexpr (STORE_T)
          C[col * M + row] = v;
        else
          C[row * Nc + col] = v;
      }
}

// ---------------- fused attention ----------------
// per block: (b, h, 64 q-rows). scores in MFMA accumulators, softmax via
// quad-group butterfly shuffles, attn -> LDS (C-layout -> A-layout), PV MFMA.
__global__ __launch_bounds__(256) void attn_kernel(
    const short* __restrict__ q,    // [B*N, D] bf16
    const short* __restrict__ kp,   // [B, E, D] bf16
    const short* __restrict__ vpT,  // [B, D, E] bf16
    float* __restrict__ out) {      // [B, N, D] fp32
  __shared__ short attn_lds[64][264];  // stride 264 to break bank aliasing

  int tid = threadIdx.x;
  int w = tid >> 6;
  int lane = tid & 63;
  int l16 = lane & 15;
  int quad = lane >> 4;
  int n0 = blockIdx.x * 64;
  int h = blockIdx.y;
  int b = blockIdx.z;
  int nrow = n0 + w * 16;

  // ---- QK^T : 16 e-tiles, K = 64 (2 k-steps) ----
  floatx4 s[16];
#pragma unroll
  for (int t = 0; t < 16; ++t) s[t] = (floatx4){0.f, 0.f, 0.f, 0.f};

  const short* qbase = q + ((size_t)(b * N_ + nrow + l16)) * D_ + h * HD_;
  bf16x8 af0 = *(const bf16x8*)(qbase + quad * 8);
  bf16x8 af1 = *(const bf16x8*)(qbase + 32 + quad * 8);

  const short* kpb = kp + (size_t)b * E_ * D_ + h * HD_;
#pragma unroll
  for (int t = 0; t < 16; ++t) {
    const short* kr = kpb + (size_t)(t * 16 + l16) * D_;
    bf16x8 b0 = *(const bf16x8*)(kr + quad * 8);
    bf16x8 b1 = *(const bf16x8*)(kr + 32 + quad * 8);
    s[t] = __builtin_amdgcn_mfma_f32_16x16x32_bf16(af0, b0, s[t], 0, 0, 0);
    s[t] = __builtin_amdgcn_mfma_f32_16x16x32_bf16(af1, b1, s[t], 0, 0, 0);
  }

  // ---- softmax (rows live in quad groups: row = quad*4 + r) ----
  float m4[4] = {-1e30f, -1e30f, -1e30f, -1e30f};
#pragma unroll
  for (int t = 0; t < 16; ++t)
#pragma unroll
    for (int r = 0; r < 4; ++r) {
      s[t][r] *= 0.125f;  // 1/sqrt(HD)
      m4[r] = fmaxf(m4[r], s[t][r]);
    }
#pragma unroll
  for (int off = 1; off < 16; off <<= 1)
#pragma unroll
    for (int r = 0; r < 4; ++r) m4[r] = fmaxf(m4[r], __shfl_xor(m4[r], off, 64));

  float l4[4] = {0.f, 0.f, 0.f, 0.f};
#pragma unroll
  for (int t = 0; t < 16; ++t)
#pragma unroll
    for (int r = 0; r < 4; ++r) {
      s[t][r] = __expf(s[t][r] - m4[r]);
      l4[r] += s[t][r];
    }
#pragma unroll
  for (int off = 1; off < 16; off <<= 1)
#pragma unroll
    for (int r = 0; r < 4; ++r) l4[r] += __shfl_xor(l4[r], off, 64);

  // ---- C-layout -> A-layout via LDS ----
#pragma unroll
  for (int t = 0; t < 16; ++t)
#pragma unroll
    for (int r = 0; r < 4; ++r)
      attn_lds[w * 16 + quad * 4 + r][t * 16 + l16] = f2bf(s[t][r]);
  __syncthreads();

  // ---- PV : out[16n x 64d], K = E = 256 (8 e-steps) ----
  floatx4 o[4];
#pragma unroll
  for (int t = 0; t < 4; ++t) o[t] = (floatx4){0.f, 0.f, 0.f, 0.f};

  const short* arow = &attn_lds[w * 16 + l16][0];
  const short* vb = vpT + (size_t)b * D_ * E_ + (size_t)(h * HD_) * E_;
#pragma unroll
  for (int es = 0; es < 8; ++es) {
    bf16x8 afr = *(const bf16x8*)(arow + es * 32 + quad * 8);
#pragma unroll
    for (int t2 = 0; t2 < 4; ++t2) {
      bf16x8 bfr = *(const bf16x8*)(vb + (size_t)(t2 * 16 + l16) * E_ + es * 32 + quad * 8);
      o[t2] = __builtin_amdgcn_mfma_f32_16x16x32_bf16(afr, bfr, o[t2], 0, 0, 0);
    }
  }

  // ---- store (divide by softmax denom; row = quad*4 + r matches l4) ----
#pragma unroll
  for (int r = 0; r < 4; ++r) {
    float inv = 1.0f / l4[r];
    int n = n0 + w * 16 + quad * 4 + r;
#pragma unroll
    for (int t2 = 0; t2 < 4; ++t2)
      out[((size_t)(b * N_ + n)) * D_ + h * HD_ + t2 * 16 + l16] = o[t2][r] * inv;
  }
}

extern "C" void kernel_launch(void* const* d_in, const int* in_sizes, int n_in,
                              void* d_out, int out_size, void* d_ws, size_t ws_size,
                              hipStream_t stream) {
  const float* x    = (const float*)d_in[0];  // [B,N,D]
  const float* proj = (const float*)d_in[1];  // [N,E]
  const float* Wq   = (const float*)d_in[2];  // [D,D]
  const float* Wk   = (const float*)d_in[3];
  const float* Wv   = (const float*)d_in[4];
  float* out = (float*)d_out;

  short* p = (short*)d_ws;
  short* xtb   = p; p += (size_t)B_ * D_ * N_;  // per-batch x^T   [b][D,N]
  short* WqT   = p; p += (size_t)D_ * D_;       // W_q^T [D,D]
  short* WkT   = p; p += (size_t)D_ * D_;
  short* WvT   = p; p += (size_t)D_ * D_;
  short* projT = p; p += (size_t)E_ * N_;       // proj^T [E,N]
  short* qb    = p; p += (size_t)B_ * N_ * D_;  // q bf16 [B*N, D]
  short* xp    = p; p += (size_t)B_ * E_ * D_;  // proj^T @ x  [b][E,D]
  short* kpb   = p; p += (size_t)B_ * E_ * D_;  // k_proj [b][E,D]
  short* vpT   = p; p += (size_t)B_ * D_ * E_;  // v_proj^T [b][D,E]

  dim3 blkT(32, 8);
  for (int b = 0; b < B_; ++b)
    transpose_cast_kernel<<<dim3(D_ / 32, N_ / 32), blkT, 0, stream>>>(
        x + (size_t)b * N_ * D_, xtb + (size_t)b * D_ * N_, N_, D_);
  transpose_cast_kernel<<<dim3(D_ / 32, D_ / 32), blkT, 0, stream>>>(Wq, WqT, D_, D_);
  transpose_cast_kernel<<<dim3(D_ / 32, D_ / 32), blkT, 0, stream>>>(Wk, WkT, D_, D_);
  transpose_cast_kernel<<<dim3(D_ / 32, D_ / 32), blkT, 0, stream>>>(Wv, WvT, D_, D_);
  transpose_cast_kernel<<<dim3(E_ / 32, N_ / 32), blkT, 0, stream>>>(proj, projT, N_, E_);

  // q = x @ W_q   (A = x fp32 cast on the fly)
  gemm_bt_kernel<true, false><<<dim3((B_ * N_) / 64, D_ / 64, 1), 256, 0, stream>>>(
      (const void*)x, WqT, qb, B_ * N_, D_, D_, 0, 0, 0);
  // xp[b] = proj^T @ x[b]   (Bt = x[b]^T)
  gemm_bt_kernel<false, false><<<dim3(E_ / 64, D_ / 64, B_), 256, 0, stream>>>(
      (const void*)projT, xtb, xp, E_, D_, N_, 0, (long)D_ * N_, (long)E_ * D_);
  // k_proj[b] = xp[b] @ W_k
  gemm_bt_kernel<false, false><<<dim3(E_ / 64, D_ / 64, B_), 256, 0, stream>>>(
      (const void*)xp, WkT, kpb, E_, D_, D_, (long)E_ * D_, 0, (long)E_ * D_);
  // v_proj[b]^T = (xp[b] @ W_v)^T  (transposed store)
  gemm_bt_kernel<false, true><<<dim3(E_ / 64, D_ / 64, B_), 256, 0, stream>>>(
      (const void*)xp, WvT, vpT, E_, D_, D_, (long)E_ * D_, 0, (long)D_ * E_);

  attn_kernel<<<dim3(N_ / 64, H_, B_), 256, 0, stream>>>(qb, kpb, vpT, out);
}

// Round 2
// 424.673 us; speedup vs baseline: 1.6650x; 1.6650x over previous
//
#include <hip/hip_runtime.h>
#include <hip/hip_bf16.h>

#define B_ 4
#define N_ 4096
#define D_ 1024
#define H_ 16
#define E_ 256
#define HD_ 64

typedef __attribute__((ext_vector_type(8))) short bf16x8;
typedef __attribute__((ext_vector_type(4))) float floatx4;

__device__ inline short f2bf(float f) {
  __hip_bfloat16 h = __float2bfloat16(f);
  short s;
  __builtin_memcpy(&s, &h, 2);
  return s;
}

// async global->LDS, 16 bytes per lane. LDS dest must be wave-uniform base +
// lane*16 (it is: our layouts put thread t's segment at byte offset t*16).
__device__ inline void gld_lds16(const short* g, short* l) {
  __builtin_amdgcn_global_load_lds(
      (const __attribute__((address_space(1))) void*)g,
      (__attribute__((address_space(3))) void*)l, 16, 0, 0);
}

// ---------------- transpose + cast fp32 -> bf16 ----------------
// src [R, C] fp32 -> dstT [C, R] bf16; if CAST_COPY also dstC [R, C] bf16.
template <bool CAST_COPY>
__global__ void transpose_cast_kernel(const float* __restrict__ src,
                                      short* __restrict__ dstT,
                                      short* __restrict__ dstC,
                                      int R, int C) {
  __shared__ float tile[32][33];
  int c0 = blockIdx.x * 32;
  int r0 = blockIdx.y * 32;
  int tx = threadIdx.x;   // 0..31
  int ty = threadIdx.y;   // 0..7
#pragma unroll
  for (int i = 0; i < 4; ++i) {
    int r = ty * 4 + i;
    float v = src[(size_t)(r0 + r) * C + (c0 + tx)];
    tile[r][tx] = v;
    if constexpr (CAST_COPY)
      dstC[(size_t)(r0 + r) * C + (c0 + tx)] = f2bf(v);
  }
  __syncthreads();
#pragma unroll
  for (int i = 0; i < 4; ++i) {
    int c = ty * 4 + i;
    dstT[(size_t)(c0 + c) * R + (r0 + tx)] = f2bf(tile[tx][c]);
  }
}

// ---------------- m97-style 128x128 LDS-staged bf16 GEMM ----------------
// C[M,Nc] = A[M,K] * Bt[Nc,K]^T, all bf16 (C stored bf16).
// 256 threads = 4 waves (2x2), wave tile 64x64 = 4x4 MFMA 16x16x32, BK=32.
__global__ __launch_bounds__(256) void gemm128_bt_kernel(
    const short* __restrict__ A, const short* __restrict__ Bt,
    short* __restrict__ C, int M, int Nc, int K) {
  __shared__ short lds_a[128 * 32];
  __shared__ short lds_b[128 * 32];
  int tid = threadIdx.x;
  int lane = tid & 63;
  int w = tid >> 6;
  int l16 = lane & 15;
  int quad = lane >> 4;
  int wm = w >> 1, wn = w & 1;
  int m0 = blockIdx.x * 128, n0 = blockIdx.y * 128;

  // staging map: thread t stages 16 B at row t>>2 (and t>>2 + 64), k-seg (t&3)*8
  int srow = tid >> 2;
  int skcol = (tid & 3) * 8;
  const short* ag = A + (size_t)(m0 + srow) * K + skcol;
  const short* bg = Bt + (size_t)(n0 + srow) * K + skcol;
  short* la = lds_a + tid * 8;          // byte offset tid*16 (wave-uniform+lane*16)
  short* lb = lds_b + tid * 8;
  const size_t half = (size_t)64 * K;

  floatx4 acc[4][4];
#pragma unroll
  for (int i = 0; i < 4; ++i)
#pragma unroll
    for (int j = 0; j < 4; ++j) acc[i][j] = (floatx4){0.f, 0.f, 0.f, 0.f};

  for (int k = 0; k < K; k += 32) {
    gld_lds16(ag + k, la);
    gld_lds16(ag + half + k, la + 64 * 32);
    gld_lds16(bg + k, lb);
    gld_lds16(bg + half + k, lb + 64 * 32);
    __syncthreads();

    bf16x8 af[4], bf[4];
#pragma unroll
    for (int mt = 0; mt < 4; ++mt)
      af[mt] = *(const bf16x8*)(lds_a + (wm * 64 + mt * 16 + l16) * 32 + quad * 8);
#pragma unroll
    for (int nt = 0; nt < 4; ++nt)
      bf[nt] = *(const bf16x8*)(lds_b + (wn * 64 + nt * 16 + l16) * 32 + quad * 8);
#pragma unroll
    for (int mt = 0; mt < 4; ++mt)
#pragma unroll
      for (int nt = 0; nt < 4; ++nt)
        acc[mt][nt] = __builtin_amdgcn_mfma_f32_16x16x32_bf16(af[mt], bf[nt], acc[mt][nt], 0, 0, 0);
    __syncthreads();
  }

#pragma unroll
  for (int mt = 0; mt < 4; ++mt)
#pragma unroll
    for (int nt = 0; nt < 4; ++nt)
#pragma unroll
      for (int r = 0; r < 4; ++r) {
        size_t row = (size_t)(m0 + wm * 64 + mt * 16 + quad * 4 + r);
        size_t col = (size_t)(n0 + wn * 64 + nt * 16 + l16);
        C[row * Nc + col] = f2bf(acc[mt][nt][r]);
      }
}

// ---------------- generic 64x64 C = A * Bt^T bf16 GEMM (small shapes) ------
template <bool STORE_T>
__global__ __launch_bounds__(256) void gemm_bt_kernel(
    const short* __restrict__ Av, const short* __restrict__ Btv,
    short* __restrict__ Cv, int M, int Nc, int K,
    long sA, long sB, long sC) {
  int tid = threadIdx.x;
  int w = tid >> 6;
  int lane = tid & 63;
  int l16 = lane & 15;
  int quad = lane >> 4;
  int m_base = blockIdx.x * 64 + (w >> 1) * 32;
  int n_base = blockIdx.y * 64 + (w & 1) * 32;

  const short* Ab = Av + (size_t)blockIdx.z * sA;
  const short* Bt = Btv + (size_t)blockIdx.z * sB;
  short* C = Cv + (size_t)blockIdx.z * sC;

  floatx4 acc[2][2];
#pragma unroll
  for (int i = 0; i < 2; ++i)
#pragma unroll
    for (int j = 0; j < 2; ++j) acc[i][j] = (floatx4){0.f, 0.f, 0.f, 0.f};

  for (int k = 0; k < K; k += 32) {
    bf16x8 a[2], b[2];
#pragma unroll
    for (int mt = 0; mt < 2; ++mt)
      a[mt] = *(const bf16x8*)(Ab + (size_t)(m_base + mt * 16 + l16) * K + k + quad * 8);
#pragma unroll
    for (int nt = 0; nt < 2; ++nt)
      b[nt] = *(const bf16x8*)(Bt + (size_t)(n_base + nt * 16 + l16) * K + k + quad * 8);
#pragma unroll
    for (int mt = 0; mt < 2; ++mt)
#pragma unroll
      for (int nt = 0; nt < 2; ++nt)
        acc[mt][nt] = __builtin_amdgcn_mfma_f32_16x16x32_bf16(a[mt], b[nt], acc[mt][nt], 0, 0, 0);
  }

#pragma unroll
  for (int mt = 0; mt < 2; ++mt)
#pragma unroll
    for (int nt = 0; nt < 2; ++nt)
#pragma unroll
      for (int r = 0; r < 4; ++r) {
        size_t row = (size_t)(m_base + mt * 16 + quad * 4 + r);
        size_t col = (size_t)(n_base + nt * 16 + l16);
        short v = f2bf(acc[mt][nt][r]);
        if constexpr (STORE_T)
          C[col * M + row] = v;
        else
          C[row * Nc + col] = v;
      }
}

// ---------------- fused attention (unchanged from round 1) ----------------
__global__ __launch_bounds__(256) void attn_kernel(
    const short* __restrict__ q,    // [B*N, D] bf16
    const short* __restrict__ kp,   // [B, E, D] bf16
    const short* __restrict__ vpT,  // [B, D, E] bf16
    float* __restrict__ out) {      // [B, N, D] fp32
  __shared__ short attn_lds[64][264];

  int tid = threadIdx.x;
  int w = tid >> 6;
  int lane = tid & 63;
  int l16 = lane & 15;
  int quad = lane >> 4;
  int n0 = blockIdx.x * 64;
  int h = blockIdx.y;
  int b = blockIdx.z;
  int nrow = n0 + w * 16;

  floatx4 s[16];
#pragma unroll
  for (int t = 0; t < 16; ++t) s[t] = (floatx4){0.f, 0.f, 0.f, 0.f};

  const short* qbase = q + ((size_t)(b * N_ + nrow + l16)) * D_ + h * HD_;
  bf16x8 af0 = *(const bf16x8*)(qbase + quad * 8);
  bf16x8 af1 = *(const bf16x8*)(qbase + 32 + quad * 8);

  const short* kpb = kp + (size_t)b * E_ * D_ + h * HD_;
#pragma unroll
  for (int t = 0; t < 16; ++t) {
    const short* kr = kpb + (size_t)(t * 16 + l16) * D_;
    bf16x8 b0 = *(const bf16x8*)(kr + quad * 8);
    bf16x8 b1 = *(const bf16x8*)(kr + 32 + quad * 8);
    s[t] = __builtin_amdgcn_mfma_f32_16x16x32_bf16(af0, b0, s[t], 0, 0, 0);
    s[t] = __builtin_amdgcn_mfma_f32_16x16x32_bf16(af1, b1, s[t], 0, 0, 0);
  }

  float m4[4] = {-1e30f, -1e30f, -1e30f, -1e30f};
#pragma unroll
  for (int t = 0; t < 16; ++t)
#pragma unroll
    for (int r = 0; r < 4; ++r) {
      s[t][r] *= 0.125f;
      m4[r] = fmaxf(m4[r], s[t][r]);
    }
#pragma unroll
  for (int off = 1; off < 16; off <<= 1)
#pragma unroll
    for (int r = 0; r < 4; ++r) m4[r] = fmaxf(m4[r], __shfl_xor(m4[r], off, 64));

  float l4[4] = {0.f, 0.f, 0.f, 0.f};
#pragma unroll
  for (int t = 0; t < 16; ++t)
#pragma unroll
    for (int r = 0; r < 4; ++r) {
      s[t][r] = __expf(s[t][r] - m4[r]);
      l4[r] += s[t][r];
    }
#pragma unroll
  for (int off = 1; off < 16; off <<= 1)
#pragma unroll
    for (int r = 0; r < 4; ++r) l4[r] += __shfl_xor(l4[r], off, 64);

#pragma unroll
  for (int t = 0; t < 16; ++t)
#pragma unroll
    for (int r = 0; r < 4; ++r)
      attn_lds[w * 16 + quad * 4 + r][t * 16 + l16] = f2bf(s[t][r]);
  __syncthreads();

  floatx4 o[4];
#pragma unroll
  for (int t = 0; t < 4; ++t) o[t] = (floatx4){0.f, 0.f, 0.f, 0.f};

  const short* arow = &attn_lds[w * 16 + l16][0];
  const short* vb = vpT + (size_t)b * D_ * E_ + (size_t)(h * HD_) * E_;
#pragma unroll
  for (int es = 0; es < 8; ++es) {
    bf16x8 afr = *(const bf16x8*)(arow + es * 32 + quad * 8);
#pragma unroll
    for (int t2 = 0; t2 < 4; ++t2) {
      bf16x8 bfr = *(const bf16x8*)(vb + (size_t)(t2 * 16 + l16) * E_ + es * 32 + quad * 8);
      o[t2] = __builtin_amdgcn_mfma_f32_16x16x32_bf16(afr, bfr, o[t2], 0, 0, 0);
    }
  }

#pragma unroll
  for (int r = 0; r < 4; ++r) {
    float inv = 1.0f / l4[r];
    int n = n0 + w * 16 + quad * 4 + r;
#pragma unroll
    for (int t2 = 0; t2 < 4; ++t2)
      out[((size_t)(b * N_ + n)) * D_ + h * HD_ + t2 * 16 + l16] = o[t2][r] * inv;
  }
}

extern "C" void kernel_launch(void* const* d_in, const int* in_sizes, int n_in,
                              void* d_out, int out_size, void* d_ws, size_t ws_size,
                              hipStream_t stream) {
  const float* x    = (const float*)d_in[0];  // [B,N,D]
  const float* proj = (const float*)d_in[1];  // [N,E]
  const float* Wq   = (const float*)d_in[2];  // [D,D]
  const float* Wk   = (const float*)d_in[3];
  const float* Wv   = (const float*)d_in[4];
  float* out = (float*)d_out;

  short* p = (short*)d_ws;
  // xtb (per-batch x^T) is dead after the xp-GEMM; qb reuses its region.
  // Safe because all launches are stream-ordered: xp-GEMM (reads xtb)
  // completes before the q-GEMM (writes qb) starts.
  short* xtb_qb = p; p += (size_t)B_ * D_ * N_;  // 33.5 MB shared region
  short* xb     = p; p += (size_t)B_ * N_ * D_;  // x cast bf16 [B*N, D]
  short* WqT    = p; p += (size_t)D_ * D_;
  short* WkT    = p; p += (size_t)D_ * D_;
  short* WvT    = p; p += (size_t)D_ * D_;
  short* projT  = p; p += (size_t)E_ * N_;       // proj^T [E, N]
  short* xp     = p; p += (size_t)B_ * E_ * D_;  // proj^T @ x  [b][E,D]
  short* kpb    = p; p += (size_t)B_ * E_ * D_;  // k_proj [b][E,D]
  short* vpT    = p; p += (size_t)B_ * D_ * E_;  // v_proj^T [b][D,E]
  short* xtb = xtb_qb;
  short* qb  = xtb_qb;

  dim3 blkT(32, 8);
  for (int b = 0; b < B_; ++b)
    transpose_cast_kernel<true><<<dim3(D_ / 32, N_ / 32), blkT, 0, stream>>>(
        x + (size_t)b * N_ * D_, xtb + (size_t)b * D_ * N_, xb + (size_t)b * N_ * D_, N_, D_);
  transpose_cast_kernel<false><<<dim3(D_ / 32, D_ / 32), blkT, 0, stream>>>(Wq, WqT, nullptr, D_, D_);
  transpose_cast_kernel<false><<<dim3(D_ / 32, D_ / 32), blkT, 0, stream>>>(Wk, WkT, nullptr, D_, D_);
  transpose_cast_kernel<false><<<dim3(D_ / 32, D_ / 32), blkT, 0, stream>>>(Wv, WvT, nullptr, D_, D_);
  transpose_cast_kernel<false><<<dim3(E_ / 32, N_ / 32), blkT, 0, stream>>>(proj, projT, nullptr, N_, E_);

  // xp[b] = proj^T @ x[b]  (reads xtb — must precede q-GEMM which overwrites it)
  gemm_bt_kernel<false><<<dim3(E_ / 64, D_ / 64, B_), 256, 0, stream>>>(
      projT, xtb, xp, E_, D_, N_, 0, (long)D_ * N_, (long)E_ * D_);

  // q = xb @ W_q  (128x128 LDS-staged MFMA GEMM; qb overwrites dead xtb)
  gemm128_bt_kernel<<<dim3((B_ * N_) / 128, D_ / 128, 1), 256, 0, stream>>>(
      xb, WqT, qb, B_ * N_, D_, D_);

  // k_proj[b] = xp[b] @ W_k ; v_proj[b]^T = (xp[b] @ W_v)^T
  gemm_bt_kernel<false><<<dim3(E_ / 64, D_ / 64, B_), 256, 0, stream>>>(
      xp, WkT, kpb, E_, D_, D_, (long)E_ * D_, 0, (long)E_ * D_);
  gemm_bt_kernel<true><<<dim3(E_ / 64, D_ / 64, B_), 256, 0, stream>>>(
      xp, WvT, vpT, E_, D_, D_, (long)E_ * D_, 0, (long)D_ * E_);

  attn_kernel<<<dim3(N_ / 64, H_, B_), 256, 0, stream>>>(qb, kpb, vpT, out);
}

// Round 3
// 405.340 us; speedup vs baseline: 1.7444x; 1.0477x over previous
//
#include <hip/hip_runtime.h>
#include <hip/hip_bf16.h>

#define B_ 4
#define N_ 4096
#define D_ 1024
#define H_ 16
#define E_ 256
#define HD_ 64

typedef __attribute__((ext_vector_type(8))) short bf16x8;
typedef __attribute__((ext_vector_type(4))) float floatx4;

__device__ inline short f2bf(float f) {
  __hip_bfloat16 h = __float2bfloat16(f);
  short s;
  __builtin_memcpy(&s, &h, 2);
  return s;
}

// async global->LDS, 16 bytes per lane (dest = wave-uniform base + lane*16)
__device__ inline void gld_lds16(const short* g, short* l) {
  __builtin_amdgcn_global_load_lds(
      (const __attribute__((address_space(1))) void*)g,
      (__attribute__((address_space(3))) void*)l, 16, 0, 0);
}

// ---------------- transpose + cast fp32 -> bf16 (shared body) ----------------
template <bool CAST_COPY>
__device__ inline void transpose_body(const float* __restrict__ src,
                                      short* __restrict__ dstT,
                                      short* __restrict__ dstC,
                                      int R, int C) {
  __shared__ float tile[32][33];
  int c0 = blockIdx.x * 32;
  int r0 = blockIdx.y * 32;
  int tx = threadIdx.x;   // 0..31
  int ty = threadIdx.y;   // 0..7
#pragma unroll
  for (int i = 0; i < 4; ++i) {
    int r = ty * 4 + i;
    float v = src[(size_t)(r0 + r) * C + (c0 + tx)];
    tile[r][tx] = v;
    if constexpr (CAST_COPY)
      dstC[(size_t)(r0 + r) * C + (c0 + tx)] = f2bf(v);
  }
  __syncthreads();
#pragma unroll
  for (int i = 0; i < 4; ++i) {
    int c = ty * 4 + i;
    dstT[(size_t)(c0 + c) * R + (r0 + tx)] = f2bf(tile[tx][c]);
  }
}

// x [B][N,D] -> xtb [B][D,N] bf16 + xb [B][N,D] bf16 (batched over z)
__global__ void transpose_x_kernel(const float* __restrict__ x,
                                   short* __restrict__ xtb,
                                   short* __restrict__ xb) {
  int b = blockIdx.z;
  transpose_body<true>(x + (size_t)b * N_ * D_, xtb + (size_t)b * D_ * N_,
                       xb + (size_t)b * N_ * D_, N_, D_);
}

// Wq/Wk/Wv [D,D] -> transposed bf16 (z selects which)
__global__ void transpose_w_kernel(const float* __restrict__ Wq,
                                   const float* __restrict__ Wk,
                                   const float* __restrict__ Wv,
                                   short* __restrict__ WqT,
                                   short* __restrict__ WkT,
                                   short* __restrict__ WvT) {
  int z = blockIdx.z;
  const float* src = (z == 0) ? Wq : (z == 1) ? Wk : Wv;
  short* dst = (z == 0) ? WqT : (z == 1) ? WkT : WvT;
  transpose_body<false>(src, dst, nullptr, D_, D_);
}

// proj [N,E] -> projT [E,N] bf16
__global__ void transpose_p_kernel(const float* __restrict__ proj,
                                   short* __restrict__ projT) {
  transpose_body<false>(proj, projT, nullptr, N_, E_);
}

// ---------------- m97-style 128x128 LDS-staged bf16 GEMM ----------------
// C[M,Nc] = A[M,K] * Bt[Nc,K]^T, all bf16.
__global__ __launch_bounds__(256) void gemm128_bt_kernel(
    const short* __restrict__ A, const short* __restrict__ Bt,
    short* __restrict__ C, int M, int Nc, int K) {
  __shared__ short lds_a[128 * 32];
  __shared__ short lds_b[128 * 32];
  int tid = threadIdx.x;
  int lane = tid & 63;
  int w = tid >> 6;
  int l16 = lane & 15;
  int quad = lane >> 4;
  int wm = w >> 1, wn = w & 1;
  int m0 = blockIdx.x * 128, n0 = blockIdx.y * 128;

  int srow = tid >> 2;
  int skcol = (tid & 3) * 8;
  const short* ag = A + (size_t)(m0 + srow) * K + skcol;
  const short* bg = Bt + (size_t)(n0 + srow) * K + skcol;
  short* la = lds_a + tid * 8;
  short* lb = lds_b + tid * 8;
  const size_t half = (size_t)64 * K;

  floatx4 acc[4][4];
#pragma unroll
  for (int i = 0; i < 4; ++i)
#pragma unroll
    for (int j = 0; j < 4; ++j) acc[i][j] = (floatx4){0.f, 0.f, 0.f, 0.f};

  for (int k = 0; k < K; k += 32) {
    gld_lds16(ag + k, la);
    gld_lds16(ag + half + k, la + 64 * 32);
    gld_lds16(bg + k, lb);
    gld_lds16(bg + half + k, lb + 64 * 32);
    __syncthreads();

    bf16x8 af[4], bf[4];
#pragma unroll
    for (int mt = 0; mt < 4; ++mt)
      af[mt] = *(const bf16x8*)(lds_a + (wm * 64 + mt * 16 + l16) * 32 + quad * 8);
#pragma unroll
    for (int nt = 0; nt < 4; ++nt)
      bf[nt] = *(const bf16x8*)(lds_b + (wn * 64 + nt * 16 + l16) * 32 + quad * 8);
#pragma unroll
    for (int mt = 0; mt < 4; ++mt)
#pragma unroll
      for (int nt = 0; nt < 4; ++nt)
        acc[mt][nt] = __builtin_amdgcn_mfma_f32_16x16x32_bf16(af[mt], bf[nt], acc[mt][nt], 0, 0, 0);
    __syncthreads();
  }

#pragma unroll
  for (int mt = 0; mt < 4; ++mt)
#pragma unroll
    for (int nt = 0; nt < 4; ++nt)
#pragma unroll
      for (int r = 0; r < 4; ++r) {
        size_t row = (size_t)(m0 + wm * 64 + mt * 16 + quad * 4 + r);
        size_t col = (size_t)(n0 + wn * 64 + nt * 16 + l16);
        C[row * Nc + col] = f2bf(acc[mt][nt][r]);
      }
}

// ---------------- generic 64x64 C = A * Bt^T bf16 GEMM (xp) ----------------
__global__ __launch_bounds__(256) void gemm_bt_kernel(
    const short* __restrict__ Av, const short* __restrict__ Btv,
    short* __restrict__ Cv, int M, int Nc, int K,
    long sA, long sB, long sC) {
  int tid = threadIdx.x;
  int w = tid >> 6;
  int lane = tid & 63;
  int l16 = lane & 15;
  int quad = lane >> 4;
  int m_base = blockIdx.x * 64 + (w >> 1) * 32;
  int n_base = blockIdx.y * 64 + (w & 1) * 32;

  const short* Ab = Av + (size_t)blockIdx.z * sA;
  const short* Bt = Btv + (size_t)blockIdx.z * sB;
  short* C = Cv + (size_t)blockIdx.z * sC;

  floatx4 acc[2][2];
#pragma unroll
  for (int i = 0; i < 2; ++i)
#pragma unroll
    for (int j = 0; j < 2; ++j) acc[i][j] = (floatx4){0.f, 0.f, 0.f, 0.f};

  for (int k = 0; k < K; k += 32) {
    bf16x8 a[2], b[2];
#pragma unroll
    for (int mt = 0; mt < 2; ++mt)
      a[mt] = *(const bf16x8*)(Ab + (size_t)(m_base + mt * 16 + l16) * K + k + quad * 8);
#pragma unroll
    for (int nt = 0; nt < 2; ++nt)
      b[nt] = *(const bf16x8*)(Bt + (size_t)(n_base + nt * 16 + l16) * K + k + quad * 8);
#pragma unroll
    for (int mt = 0; mt < 2; ++mt)
#pragma unroll
      for (int nt = 0; nt < 2; ++nt)
        acc[mt][nt] = __builtin_amdgcn_mfma_f32_16x16x32_bf16(a[mt], b[nt], acc[mt][nt], 0, 0, 0);
  }

#pragma unroll
  for (int mt = 0; mt < 2; ++mt)
#pragma unroll
    for (int nt = 0; nt < 2; ++nt)
#pragma unroll
      for (int r = 0; r < 4; ++r) {
        size_t row = (size_t)(m_base + mt * 16 + quad * 4 + r);
        size_t col = (size_t)(n_base + nt * 16 + l16);
        C[row * Nc + col] = f2bf(acc[mt][nt][r]);
      }
}

// ---------------- merged k/v projection GEMM ----------------
// kpb[b][E,D] = xp[b] @ Wk ; vpT[b][D,E] = (xp[b] @ Wv)^T — shares A-fragments.
__global__ __launch_bounds__(256) void gemm_kv_kernel(
    const short* __restrict__ xp, const short* __restrict__ WkT,
    const short* __restrict__ WvT, short* __restrict__ kpb,
    short* __restrict__ vpT) {
  int tid = threadIdx.x;
  int w = tid >> 6;
  int lane = tid & 63;
  int l16 = lane & 15;
  int quad = lane >> 4;
  int m_base = blockIdx.x * 64 + (w >> 1) * 32;  // E dim
  int n_base = blockIdx.y * 64 + (w & 1) * 32;   // D dim
  int b = blockIdx.z;

  const short* Ab = xp + (size_t)b * E_ * D_;
  short* Ck = kpb + (size_t)b * E_ * D_;
  short* Cv = vpT + (size_t)b * D_ * E_;

  floatx4 acck[2][2], accv[2][2];
#pragma unroll
  for (int i = 0; i < 2; ++i)
#pragma unroll
    for (int j = 0; j < 2; ++j) {
      acck[i][j] = (floatx4){0.f, 0.f, 0.f, 0.f};
      accv[i][j] = (floatx4){0.f, 0.f, 0.f, 0.f};
    }

  for (int k = 0; k < D_; k += 32) {
    bf16x8 a[2], bk[2], bv[2];
#pragma unroll
    for (int mt = 0; mt < 2; ++mt)
      a[mt] = *(const bf16x8*)(Ab + (size_t)(m_base + mt * 16 + l16) * D_ + k + quad * 8);
#pragma unroll
    for (int nt = 0; nt < 2; ++nt) {
      size_t off = (size_t)(n_base + nt * 16 + l16) * D_ + k + quad * 8;
      bk[nt] = *(const bf16x8*)(WkT + off);
      bv[nt] = *(const bf16x8*)(WvT + off);
    }
#pragma unroll
    for (int mt = 0; mt < 2; ++mt)
#pragma unroll
      for (int nt = 0; nt < 2; ++nt) {
        acck[mt][nt] = __builtin_amdgcn_mfma_f32_16x16x32_bf16(a[mt], bk[nt], acck[mt][nt], 0, 0, 0);
        accv[mt][nt] = __builtin_amdgcn_mfma_f32_16x16x32_bf16(a[mt], bv[nt], accv[mt][nt], 0, 0, 0);
      }
  }

#pragma unroll
  for (int mt = 0; mt < 2; ++mt)
#pragma unroll
    for (int nt = 0; nt < 2; ++nt)
#pragma unroll
      for (int r = 0; r < 4; ++r) {
        size_t row = (size_t)(m_base + mt * 16 + quad * 4 + r);  // E index
        size_t col = (size_t)(n_base + nt * 16 + l16);           // D index
        Ck[row * D_ + col] = f2bf(acck[mt][nt][r]);
        Cv[col * E_ + row] = f2bf(accv[mt][nt][r]);
      }
}

// ---------------- fused attention ----------------
// Per block: (b, h, 64 q-rows), 4 waves, each wave owns 16 q-rows.
// P LDS is strictly wave-private -> no barriers; E processed in 2 halves of
// 128 cols to halve LDS (17.4 KB -> 6 blocks/CU, VGPR-limited).
__global__ __launch_bounds__(256) void attn_kernel(
    const short* __restrict__ q,    // [B*N, D] bf16
    const short* __restrict__ kp,   // [B, E, D] bf16
    const short* __restrict__ vpT,  // [B, D, E] bf16
    float* __restrict__ out) {      // [B, N, D] fp32
  __shared__ short plds[4][16][136];  // per-wave 16 x 128 (+8 pad)

  int tid = threadIdx.x;
  int w = tid >> 6;
  int lane = tid & 63;
  int l16 = lane & 15;
  int quad = lane >> 4;
  int n0 = blockIdx.x * 64;
  int h = blockIdx.y;
  int b = blockIdx.z;
  int nrow = n0 + w * 16;

  // ---- QK^T : 16 e-tiles, K = 64 ----
  floatx4 s[16];
#pragma unroll
  for (int t = 0; t < 16; ++t) s[t] = (floatx4){0.f, 0.f, 0.f, 0.f};

  const short* qbase = q + ((size_t)(b * N_ + nrow + l16)) * D_ + h * HD_;
  bf16x8 af0 = *(const bf16x8*)(qbase + quad * 8);
  bf16x8 af1 = *(const bf16x8*)(qbase + 32 + quad * 8);

  const short* kpb = kp + (size_t)b * E_ * D_ + h * HD_;
#pragma unroll
  for (int t = 0; t < 16; ++t) {
    const short* kr = kpb + (size_t)(t * 16 + l16) * D_;
    bf16x8 b0 = *(const bf16x8*)(kr + quad * 8);
    bf16x8 b1 = *(const bf16x8*)(kr + 32 + quad * 8);
    s[t] = __builtin_amdgcn_mfma_f32_16x16x32_bf16(af0, b0, s[t], 0, 0, 0);
    s[t] = __builtin_amdgcn_mfma_f32_16x16x32_bf16(af1, b1, s[t], 0, 0, 0);
  }

  // ---- softmax (row = quad*4 + r; reduce over l16 group) ----
  float m4[4] = {-1e30f, -1e30f, -1e30f, -1e30f};
#pragma unroll
  for (int t = 0; t < 16; ++t)
#pragma unroll
    for (int r = 0; r < 4; ++r) {
      s[t][r] *= 0.125f;  // 1/sqrt(HD)
      m4[r] = fmaxf(m4[r], s[t][r]);
    }
#pragma unroll
  for (int off = 1; off < 16; off <<= 1)
#pragma unroll
    for (int r = 0; r < 4; ++r) m4[r] = fmaxf(m4[r], __shfl_xor(m4[r], off, 64));

  float l4[4] = {0.f, 0.f, 0.f, 0.f};
#pragma unroll
  for (int t = 0; t < 16; ++t)
#pragma unroll
    for (int r = 0; r < 4; ++r) {
      s[t][r] = __expf(s[t][r] - m4[r]);
      l4[r] += s[t][r];
    }
#pragma unroll
  for (int off = 1; off < 16; off <<= 1)
#pragma unroll
    for (int r = 0; r < 4; ++r) l4[r] += __shfl_xor(l4[r], off, 64);

  // ---- PV in two E-halves: C-layout -> A-layout via wave-private LDS ----
  floatx4 o[4];
#pragma unroll
  for (int t = 0; t < 4; ++t) o[t] = (floatx4){0.f, 0.f, 0.f, 0.f};

  const short* vb = vpT + (size_t)b * D_ * E_ + (size_t)(h * HD_) * E_;
#pragma unroll
  for (int half = 0; half < 2; ++half) {
#pragma unroll
    for (int t = 0; t < 8; ++t)
#pragma unroll
      for (int r = 0; r < 4; ++r)
        plds[w][quad * 4 + r][t * 16 + l16] = f2bf(s[half * 8 + t][r]);

    const short* arow = &plds[w][l16][0];
#pragma unroll
    for (int es2 = 0; es2 < 4; ++es2) {
      bf16x8 afr = *(const bf16x8*)(arow + es2 * 32 + quad * 8);
      int es = half * 4 + es2;
#pragma unroll
      for (int t2 = 0; t2 < 4; ++t2) {
        bf16x8 bfr = *(const bf16x8*)(vb + (size_t)(t2 * 16 + l16) * E_ + es * 32 + quad * 8);
        o[t2] = __builtin_amdgcn_mfma_f32_16x16x32_bf16(afr, bfr, o[t2], 0, 0, 0);
      }
    }
  }

  // ---- store ----
#pragma unroll
  for (int r = 0; r < 4; ++r) {
    float inv = 1.0f / l4[r];
    int n = n0 + w * 16 + quad * 4 + r;
#pragma unroll
    for (int t2 = 0; t2 < 4; ++t2)
      out[((size_t)(b * N_ + n)) * D_ + h * HD_ + t2 * 16 + l16] = o[t2][r] * inv;
  }
}

extern "C" void kernel_launch(void* const* d_in, const int* in_sizes, int n_in,
                              void* d_out, int out_size, void* d_ws, size_t ws_size,
                              hipStream_t stream) {
  const float* x    = (const float*)d_in[0];  // [B,N,D]
  const float* proj = (const float*)d_in[1];  // [N,E]
  const float* Wq   = (const float*)d_in[2];  // [D,D]
  const float* Wk   = (const float*)d_in[3];
  const float* Wv   = (const float*)d_in[4];
  float* out = (float*)d_out;

  short* p = (short*)d_ws;
  // xtb (per-batch x^T) is dead after the xp-GEMM; qb reuses its region
  // (stream ordering: xp-GEMM reads xtb before q-GEMM writes qb).
  short* xtb_qb = p; p += (size_t)B_ * D_ * N_;
  short* xb     = p; p += (size_t)B_ * N_ * D_;
  short* WqT    = p; p += (size_t)D_ * D_;
  short* WkT    = p; p += (size_t)D_ * D_;
  short* WvT    = p; p += (size_t)D_ * D_;
  short* projT  = p; p += (size_t)E_ * N_;
  short* xp     = p; p += (size_t)B_ * E_ * D_;
  short* kpb    = p; p += (size_t)B_ * E_ * D_;
  short* vpT    = p; p += (size_t)B_ * D_ * E_;
  short* xtb = xtb_qb;
  short* qb  = xtb_qb;

  dim3 blkT(32, 8);
  transpose_x_kernel<<<dim3(D_ / 32, N_ / 32, B_), blkT, 0, stream>>>(x, xtb, xb);
  transpose_w_kernel<<<dim3(D_ / 32, D_ / 32, 3), blkT, 0, stream>>>(Wq, Wk, Wv, WqT, WkT, WvT);
  transpose_p_kernel<<<dim3(E_ / 32, N_ / 32, 1), blkT, 0, stream>>>(proj, projT);

  // xp[b] = proj^T @ x[b]  (reads xtb — must precede q-GEMM which overwrites it)
  gemm_bt_kernel<<<dim3(E_ / 64, D_ / 64, B_), 256, 0, stream>>>(
      projT, xtb, xp, E_, D_, N_, 0, (long)D_ * N_, (long)E_ * D_);

  // q = xb @ W_q  (128x128 LDS-staged; qb overwrites dead xtb)
  gemm128_bt_kernel<<<dim3((B_ * N_) / 128, D_ / 128, 1), 256, 0, stream>>>(
      xb, WqT, qb, B_ * N_, D_, D_);

  // k_proj / v_proj^T fused (shared A-fragments)
  gemm_kv_kernel<<<dim3(E_ / 64, D_ / 64, B_), 256, 0, stream>>>(
      xp, WkT, WvT, kpb, vpT);

  attn_kernel<<<dim3(N_ / 64, H_, B_), 256, 0, stream>>>(qb, kpb, vpT, out);
}

// Round 4
// 339.793 us; speedup vs baseline: 2.0809x; 1.1929x over previous
//
#include <hip/hip_runtime.h>
#include <hip/hip_bf16.h>

#define B_ 4
#define N_ 4096
#define D_ 1024
#define H_ 16
#define E_ 256
#define HD_ 64

typedef __attribute__((ext_vector_type(8))) short bf16x8;
typedef __attribute__((ext_vector_type(4))) float floatx4;

__device__ inline short f2bf(float f) {
  __hip_bfloat16 h = __float2bfloat16(f);
  short s;
  __builtin_memcpy(&s, &h, 2);
  return s;
}

// async global->LDS, 16 bytes per lane (dest = wave-uniform base + lane*16)
__device__ inline void gld_lds16(const short* g, short* l) {
  __builtin_amdgcn_global_load_lds(
      (const __attribute__((address_space(1))) void*)g,
      (__attribute__((address_space(3))) void*)l, 16, 0, 0);
}

// ---------------- transpose + cast fp32 -> bf16 (shared body) ----------------
template <bool CAST_COPY>
__device__ inline void transpose_body(const float* __restrict__ src,
                                      short* __restrict__ dstT,
                                      short* __restrict__ dstC,
                                      int R, int C) {
  __shared__ float tile[32][33];
  int c0 = blockIdx.x * 32;
  int r0 = blockIdx.y * 32;
  int tx = threadIdx.x;   // 0..31
  int ty = threadIdx.y;   // 0..7
#pragma unroll
  for (int i = 0; i < 4; ++i) {
    int r = ty * 4 + i;
    float v = src[(size_t)(r0 + r) * C + (c0 + tx)];
    tile[r][tx] = v;
    if constexpr (CAST_COPY)
      dstC[(size_t)(r0 + r) * C + (c0 + tx)] = f2bf(v);
  }
  __syncthreads();
#pragma unroll
  for (int i = 0; i < 4; ++i) {
    int c = ty * 4 + i;
    dstT[(size_t)(c0 + c) * R + (r0 + tx)] = f2bf(tile[tx][c]);
  }
}

__global__ void transpose_x_kernel(const float* __restrict__ x,
                                   short* __restrict__ xtb,
                                   short* __restrict__ xb) {
  int b = blockIdx.z;
  transpose_body<true>(x + (size_t)b * N_ * D_, xtb + (size_t)b * D_ * N_,
                       xb + (size_t)b * N_ * D_, N_, D_);
}

__global__ void transpose_w_kernel(const float* __restrict__ Wq,
                                   const float* __restrict__ Wk,
                                   const float* __restrict__ Wv,
                                   short* __restrict__ WqT,
                                   short* __restrict__ WkT,
                                   short* __restrict__ WvT) {
  int z = blockIdx.z;
  const float* src = (z == 0) ? Wq : (z == 1) ? Wk : Wv;
  short* dst = (z == 0) ? WqT : (z == 1) ? WkT : WvT;
  transpose_body<false>(src, dst, nullptr, D_, D_);
}

__global__ void transpose_p_kernel(const float* __restrict__ proj,
                                   short* __restrict__ projT) {
  transpose_body<false>(proj, projT, nullptr, N_, E_);
}

// ---------------- m97-style 128x128 LDS-staged bf16 GEMM (batched) ----------
// C[M,Nc] = A[M,K] * Bt[Nc,K]^T per z (strides sA/sB/sC elements).
__global__ __launch_bounds__(256) void gemm128_bt_kernel(
    const short* __restrict__ Ag, const short* __restrict__ Btg,
    short* __restrict__ Cg, int M, int Nc, int K,
    long sA, long sB, long sC) {
  __shared__ short lds_a[128 * 32];
  __shared__ short lds_b[128 * 32];
  int tid = threadIdx.x;
  int lane = tid & 63;
  int w = tid >> 6;
  int l16 = lane & 15;
  int quad = lane >> 4;
  int wm = w >> 1, wn = w & 1;
  int m0 = blockIdx.x * 128, n0 = blockIdx.y * 128;

  const short* A = Ag + (size_t)blockIdx.z * sA;
  const short* Bt = Btg + (size_t)blockIdx.z * sB;
  short* C = Cg + (size_t)blockIdx.z * sC;

  int srow = tid >> 2;
  int skcol = (tid & 3) * 8;
  const short* ag = A + (size_t)(m0 + srow) * K + skcol;
  const short* bg = Bt + (size_t)(n0 + srow) * K + skcol;
  short* la = lds_a + tid * 8;
  short* lb = lds_b + tid * 8;
  const size_t half = (size_t)64 * K;

  floatx4 acc[4][4];
#pragma unroll
  for (int i = 0; i < 4; ++i)
#pragma unroll
    for (int j = 0; j < 4; ++j) acc[i][j] = (floatx4){0.f, 0.f, 0.f, 0.f};

  for (int k = 0; k < K; k += 32) {
    gld_lds16(ag + k, la);
    gld_lds16(ag + half + k, la + 64 * 32);
    gld_lds16(bg + k, lb);
    gld_lds16(bg + half + k, lb + 64 * 32);
    __syncthreads();

    bf16x8 af[4], bf[4];
#pragma unroll
    for (int mt = 0; mt < 4; ++mt)
      af[mt] = *(const bf16x8*)(lds_a + (wm * 64 + mt * 16 + l16) * 32 + quad * 8);
#pragma unroll
    for (int nt = 0; nt < 4; ++nt)
      bf[nt] = *(const bf16x8*)(lds_b + (wn * 64 + nt * 16 + l16) * 32 + quad * 8);
#pragma unroll
    for (int mt = 0; mt < 4; ++mt)
#pragma unroll
      for (int nt = 0; nt < 4; ++nt)
        acc[mt][nt] = __builtin_amdgcn_mfma_f32_16x16x32_bf16(af[mt], bf[nt], acc[mt][nt], 0, 0, 0);
    __syncthreads();
  }

#pragma unroll
  for (int mt = 0; mt < 4; ++mt)
#pragma unroll
    for (int nt = 0; nt < 4; ++nt)
#pragma unroll
      for (int r = 0; r < 4; ++r) {
        size_t row = (size_t)(m0 + wm * 64 + mt * 16 + quad * 4 + r);
        size_t col = (size_t)(n0 + wn * 64 + nt * 16 + l16);
        C[row * Nc + col] = f2bf(acc[mt][nt][r]);
      }
}

// ---------------- merged k/v projection GEMM ----------------
__global__ __launch_bounds__(256) void gemm_kv_kernel(
    const short* __restrict__ xp, const short* __restrict__ WkT,
    const short* __restrict__ WvT, short* __restrict__ kpb,
    short* __restrict__ vpT) {
  int tid = threadIdx.x;
  int w = tid >> 6;
  int lane = tid & 63;
  int l16 = lane & 15;
  int quad = lane >> 4;
  int m_base = blockIdx.x * 64 + (w >> 1) * 32;  // E dim
  int n_base = blockIdx.y * 64 + (w & 1) * 32;   // D dim
  int b = blockIdx.z;

  const short* Ab = xp + (size_t)b * E_ * D_;
  short* Ck = kpb + (size_t)b * E_ * D_;
  short* Cv = vpT + (size_t)b * D_ * E_;

  floatx4 acck[2][2], accv[2][2];
#pragma unroll
  for (int i = 0; i < 2; ++i)
#pragma unroll
    for (int j = 0; j < 2; ++j) {
      acck[i][j] = (floatx4){0.f, 0.f, 0.f, 0.f};
      accv[i][j] = (floatx4){0.f, 0.f, 0.f, 0.f};
    }

  for (int k = 0; k < D_; k += 32) {
    bf16x8 a[2], bk[2], bv[2];
#pragma unroll
    for (int mt = 0; mt < 2; ++mt)
      a[mt] = *(const bf16x8*)(Ab + (size_t)(m_base + mt * 16 + l16) * D_ + k + quad * 8);
#pragma unroll
    for (int nt = 0; nt < 2; ++nt) {
      size_t off = (size_t)(n_base + nt * 16 + l16) * D_ + k + quad * 8;
      bk[nt] = *(const bf16x8*)(WkT + off);
      bv[nt] = *(const bf16x8*)(WvT + off);
    }
#pragma unroll
    for (int mt = 0; mt < 2; ++mt)
#pragma unroll
      for (int nt = 0; nt < 2; ++nt) {
        acck[mt][nt] = __builtin_amdgcn_mfma_f32_16x16x32_bf16(a[mt], bk[nt], acck[mt][nt], 0, 0, 0);
        accv[mt][nt] = __builtin_amdgcn_mfma_f32_16x16x32_bf16(a[mt], bv[nt], accv[mt][nt], 0, 0, 0);
      }
  }

#pragma unroll
  for (int mt = 0; mt < 2; ++mt)
#pragma unroll
    for (int nt = 0; nt < 2; ++nt)
#pragma unroll
      for (int r = 0; r < 4; ++r) {
        size_t row = (size_t)(m_base + mt * 16 + quad * 4 + r);  // E index
        size_t col = (size_t)(n_base + nt * 16 + l16);           // D index
        Ck[row * D_ + col] = f2bf(acck[mt][nt][r]);
        Cv[col * E_ + row] = f2bf(accv[mt][nt][r]);
      }
}

// ---------------- fused attention v3 ----------------
// Block: (b, h, 128 q-rows), 512 threads = 8 waves, wave w owns rows w*16..+15.
// kp (256x64) and vpT (64x256) tiles staged to LDS via global_load_lds with
// XOR seg-swizzle (global->LDS map permuted; LDS stays contiguous as required).
// QK^T computed transposed (A=kp, B=q -> S^T: lane l16 = q-row, quad*4+r = e),
// so softmax reduces with 2 shuffles. kp LDS region is then reused for
// wave-private P chunks (padded, E in 2 halves). PV: A=P, B=vpT -> coalesced
// C-layout store.
__global__ __launch_bounds__(512) void attn_kernel(
    const short* __restrict__ q,    // [B*N, D] bf16
    const short* __restrict__ kp,   // [B, E, D] bf16
    const short* __restrict__ vpT,  // [B, D, E] bf16
    float* __restrict__ out) {      // [B, N, D] fp32
  __shared__ short lds_kp_p[17408];  // 34816 B: kp tile (32768 B) then P (34816 B)
  __shared__ short lds_vp[16384];    // 32768 B: vpT tile

  int tid = threadIdx.x;
  int w = tid >> 6;
  int lane = tid & 63;
  int l16 = lane & 15;
  int quad = lane >> 4;
  int n0 = blockIdx.x * 128;
  int h = blockIdx.y;
  int b = blockIdx.z;

  // ---- stage kp tile: row e (0..255) x 8 segs(16B); seg stored at s^(row&7)
  {
    const short* kpg = kp + (size_t)b * E_ * D_ + h * 64;
    int r0 = tid >> 3;                       // + j*64 (j*64 % 8 == 0)
    int sseg = (tid & 7) ^ (r0 & 7);         // global seg for LDS slot tid&7
#pragma unroll
    for (int j = 0; j < 4; ++j)
      gld_lds16(kpg + (size_t)(r0 + j * 64) * D_ + sseg * 8,
                lds_kp_p + j * 4096 + tid * 8);
  }
  // ---- stage vpT tile: row d-local (0..63) x 32 segs(16B); low-3 swizzle
  {
    const short* vpg = vpT + (size_t)b * D_ * E_ + (size_t)(h * 64) * E_;
    int s1 = tid & 31;
    int rb = tid >> 5;                       // + j*16 (j*16 % 8 == 0)
    int sseg = (s1 & 24) | ((s1 & 7) ^ (rb & 7));
#pragma unroll
    for (int j = 0; j < 4; ++j)
      gld_lds16(vpg + (size_t)(rb + j * 16) * E_ + sseg * 8,
                lds_vp + j * 4096 + tid * 8);
  }

  // q fragments (B-operand: lane l16 = q-row) — issue before barrier
  const short* qbase = q + ((size_t)(b * N_ + n0 + w * 16 + l16)) * D_ + h * 64;
  bf16x8 qf0 = *(const bf16x8*)(qbase + quad * 8);
  bf16x8 qf1 = *(const bf16x8*)(qbase + 32 + quad * 8);

  __syncthreads();

  // ---- QK^T (transposed): S^T tiles, A = kp rows from LDS ----
  floatx4 s[16];
#pragma unroll
  for (int t = 0; t < 16; ++t) s[t] = (floatx4){0.f, 0.f, 0.f, 0.f};

  int sw = l16 & 7;
#pragma unroll
  for (int t = 0; t < 16; ++t) {
    int r = t * 16 + l16;                    // kp row (e); r&7 == l16&7
    const short* rowp = lds_kp_p + r * 64;
    bf16x8 a0 = *(const bf16x8*)(rowp + ((quad) ^ sw) * 8);
    bf16x8 a1 = *(const bf16x8*)(rowp + ((4 + quad) ^ sw) * 8);
    s[t] = __builtin_amdgcn_mfma_f32_16x16x32_bf16(a0, qf0, s[t], 0, 0, 0);
    s[t] = __builtin_amdgcn_mfma_f32_16x16x32_bf16(a1, qf1, s[t], 0, 0, 0);
  }

  // ---- softmax over e (per lane: e = t*16 + quad*4 + r; reduce over quads) --
  float mx = -1e30f;
#pragma unroll
  for (int t = 0; t < 16; ++t)
#pragma unroll
    for (int r = 0; r < 4; ++r) {
      s[t][r] *= 0.125f;  // 1/sqrt(HD)
      mx = fmaxf(mx, s[t][r]);
    }
  mx = fmaxf(mx, __shfl_xor(mx, 16, 64));
  mx = fmaxf(mx, __shfl_xor(mx, 32, 64));

  float lsum = 0.f;
#pragma unroll
  for (int t = 0; t < 16; ++t)
#pragma unroll
    for (int r = 0; r < 4; ++r) {
      s[t][r] = __expf(s[t][r] - mx);
      lsum += s[t][r];
    }
  lsum += __shfl_xor(lsum, 16, 64);
  lsum += __shfl_xor(lsum, 32, 64);

  // ---- all waves done reading kp region -> reuse it for P ----
  __syncthreads();

  short* pbase = lds_kp_p + w * 2176;  // per-wave 16 rows x 136 shorts (4352 B)
  floatx4 o4[4];
#pragma unroll
  for (int t2 = 0; t2 < 4; ++t2) o4[t2] = (floatx4){0.f, 0.f, 0.f, 0.f};

#pragma unroll
  for (int hf = 0; hf < 2; ++hf) {
    // write P chunk: row = n-local = l16 (lane's own q-row), col e-local
#pragma unroll
    for (int t = 0; t < 8; ++t)
#pragma unroll
      for (int r = 0; r < 4; ++r)
        pbase[l16 * 136 + t * 16 + quad * 4 + r] = f2bf(s[hf * 8 + t][r]);

#pragma unroll
    for (int es2 = 0; es2 < 4; ++es2) {
      bf16x8 pa = *(const bf16x8*)(pbase + l16 * 136 + es2 * 32 + quad * 8);
      int es = hf * 4 + es2;
#pragma unroll
      for (int t2 = 0; t2 < 4; ++t2) {
        int rr = t2 * 16 + l16;              // vp row (d-local); rr&7 == l16&7
        int seg = es * 4 + quad;
        int sg = (seg & 24) | ((seg & 7) ^ sw);
        bf16x8 vf = *(const bf16x8*)(lds_vp + rr * 256 + sg * 8);
        o4[t2] = __builtin_amdgcn_mfma_f32_16x16x32_bf16(pa, vf, o4[t2], 0, 0, 0);
      }
    }
  }

  // ---- store: C-layout row = n-local = quad*4+r; fetch that row's denom ----
  float linv[4];
#pragma unroll
  for (int r = 0; r < 4; ++r)
    linv[r] = 1.0f / __shfl(lsum, (lane & 48) | (quad * 4 + r), 64);

#pragma unroll
  for (int r = 0; r < 4; ++r) {
    int n = n0 + w * 16 + quad * 4 + r;
#pragma unroll
    for (int t2 = 0; t2 < 4; ++t2)
      out[((size_t)(b * N_ + n)) * D_ + h * 64 + t2 * 16 + l16] = o4[t2][r] * linv[r];
  }
}

extern "C" void kernel_launch(void* const* d_in, const int* in_sizes, int n_in,
                              void* d_out, int out_size, void* d_ws, size_t ws_size,
                              hipStream_t stream) {
  const float* x    = (const float*)d_in[0];  // [B,N,D]
  const float* proj = (const float*)d_in[1];  // [N,E]
  const float* Wq   = (const float*)d_in[2];  // [D,D]
  const float* Wk   = (const float*)d_in[3];
  const float* Wv   = (const float*)d_in[4];
  float* out = (float*)d_out;

  short* p = (short*)d_ws;
  // xtb (per-batch x^T) is dead after the xp-GEMM; qb reuses its region
  // (stream ordering: xp-GEMM reads xtb before q-GEMM writes qb).
  short* xtb_qb = p; p += (size_t)B_ * D_ * N_;
  short* xb     = p; p += (size_t)B_ * N_ * D_;
  short* WqT    = p; p += (size_t)D_ * D_;
  short* WkT    = p; p += (size_t)D_ * D_;
  short* WvT    = p; p += (size_t)D_ * D_;
  short* projT  = p; p += (size_t)E_ * N_;
  short* xp     = p; p += (size_t)B_ * E_ * D_;
  short* kpb    = p; p += (size_t)B_ * E_ * D_;
  short* vpT    = p; p += (size_t)B_ * D_ * E_;
  short* xtb = xtb_qb;
  short* qb  = xtb_qb;

  dim3 blkT(32, 8);
  transpose_x_kernel<<<dim3(D_ / 32, N_ / 32, B_), blkT, 0, stream>>>(x, xtb, xb);
  transpose_w_kernel<<<dim3(D_ / 32, D_ / 32, 3), blkT, 0, stream>>>(Wq, Wk, Wv, WqT, WkT, WvT);
  transpose_p_kernel<<<dim3(E_ / 32, N_ / 32, 1), blkT, 0, stream>>>(proj, projT);

  // xp[b] = proj^T @ x[b]  (128-tile; reads xtb — must precede q-GEMM)
  gemm128_bt_kernel<<<dim3(E_ / 128, D_ / 128, B_), 256, 0, stream>>>(
      projT, xtb, xp, E_, D_, N_, 0, (long)D_ * N_, (long)E_ * D_);

  // q = xb @ W_q  (128-tile; qb overwrites dead xtb)
  gemm128_bt_kernel<<<dim3((B_ * N_) / 128, D_ / 128, 1), 256, 0, stream>>>(
      xb, WqT, qb, B_ * N_, D_, D_, 0, 0, 0);

  // k_proj / v_proj^T fused (shared A-fragments)
  gemm_kv_kernel<<<dim3(E_ / 64, D_ / 64, B_), 256, 0, stream>>>(
      xp, WkT, WvT, kpb, vpT);

  attn_kernel<<<dim3(N_ / 128, H_, B_), 512, 0, stream>>>(qb, kpb, vpT, out);
}

// Round 5
// 304.897 us; speedup vs baseline: 2.3190x; 1.1145x over previous
//
#include <hip/hip_runtime.h>
#include <hip/hip_bf16.h>

#define B_ 4
#define N_ 4096
#define D_ 1024
#define H_ 16
#define E_ 256
#define HD_ 64

typedef __attribute__((ext_vector_type(8))) short bf16x8;
typedef __attribute__((ext_vector_type(4))) short shortx4;
typedef __attribute__((ext_vector_type(4))) float floatx4;

__device__ inline short f2bf(float f) {
  __hip_bfloat16 h = __float2bfloat16(f);
  short s;
  __builtin_memcpy(&s, &h, 2);
  return s;
}

// async global->LDS, 16 bytes per lane (dest = wave-uniform base + lane*16)
__device__ inline void gld_lds16(const short* g, short* l) {
  __builtin_amdgcn_global_load_lds(
      (const __attribute__((address_space(1))) void*)g,
      (__attribute__((address_space(3))) void*)l, 16, 0, 0);
}

// ---------------- transpose + cast fp32 -> bf16 (shared body) ----------------
template <bool CAST_COPY>
__device__ inline void transpose_body(const float* __restrict__ src,
                                      short* __restrict__ dstT,
                                      short* __restrict__ dstC,
                                      int R, int C) {
  __shared__ float tile[32][33];
  int c0 = blockIdx.x * 32;
  int r0 = blockIdx.y * 32;
  int tx = threadIdx.x;   // 0..31
  int ty = threadIdx.y;   // 0..7
#pragma unroll
  for (int i = 0; i < 4; ++i) {
    int r = ty * 4 + i;
    float v = src[(size_t)(r0 + r) * C + (c0 + tx)];
    tile[r][tx] = v;
    if constexpr (CAST_COPY)
      dstC[(size_t)(r0 + r) * C + (c0 + tx)] = f2bf(v);
  }
  __syncthreads();
#pragma unroll
  for (int i = 0; i < 4; ++i) {
    int c = ty * 4 + i;
    dstT[(size_t)(c0 + c) * R + (r0 + tx)] = f2bf(tile[tx][c]);
  }
}

__global__ void transpose_x_kernel(const float* __restrict__ x,
                                   short* __restrict__ xtb,
                                   short* __restrict__ xb) {
  int b = blockIdx.z;
  transpose_body<true>(x + (size_t)b * N_ * D_, xtb + (size_t)b * D_ * N_,
                       xb + (size_t)b * N_ * D_, N_, D_);
}

__global__ void transpose_w_kernel(const float* __restrict__ Wq,
                                   const float* __restrict__ Wk,
                                   const float* __restrict__ Wv,
                                   short* __restrict__ WqT,
                                   short* __restrict__ WkT,
                                   short* __restrict__ WvT) {
  int z = blockIdx.z;
  const float* src = (z == 0) ? Wq : (z == 1) ? Wk : Wv;
  short* dst = (z == 0) ? WqT : (z == 1) ? WkT : WvT;
  transpose_body<false>(src, dst, nullptr, D_, D_);
}

__global__ void transpose_p_kernel(const float* __restrict__ proj,
                                   short* __restrict__ projT) {
  transpose_body<false>(proj, projT, nullptr, N_, E_);
}

// ---------------- fp32 -> bf16 cast (for split-K result) ----------------
__global__ void cast_f32_bf16_kernel(const float* __restrict__ in,
                                     short* __restrict__ out) {
  int i = (blockIdx.x * 256 + threadIdx.x) * 4;
  const float4 v = *(const float4*)(in + i);
  shortx4 o;
  o[0] = f2bf(v.x); o[1] = f2bf(v.y); o[2] = f2bf(v.z); o[3] = f2bf(v.w);
  *(shortx4*)(out + i) = o;
}

// ---------------- m97-style 128x128 LDS-staged bf16 GEMM (batched) ----------
// C[M,Nc] = A[M,K] * Bt[Nc,K]^T per z (strides sA/sB/sC elements).
__global__ __launch_bounds__(256) void gemm128_bt_kernel(
    const short* __restrict__ Ag, const short* __restrict__ Btg,
    short* __restrict__ Cg, int M, int Nc, int K,
    long sA, long sB, long sC) {
  __shared__ short lds_a[128 * 32];
  __shared__ short lds_b[128 * 32];
  int tid = threadIdx.x;
  int lane = tid & 63;
  int w = tid >> 6;
  int l16 = lane & 15;
  int quad = lane >> 4;
  int wm = w >> 1, wn = w & 1;
  int m0 = blockIdx.x * 128, n0 = blockIdx.y * 128;

  const short* A = Ag + (size_t)blockIdx.z * sA;
  const short* Bt = Btg + (size_t)blockIdx.z * sB;
  short* C = Cg + (size_t)blockIdx.z * sC;

  int srow = tid >> 2;
  int skcol = (tid & 3) * 8;
  const short* ag = A + (size_t)(m0 + srow) * K + skcol;
  const short* bg = Bt + (size_t)(n0 + srow) * K + skcol;
  short* la = lds_a + tid * 8;
  short* lb = lds_b + tid * 8;
  const size_t half = (size_t)64 * K;

  floatx4 acc[4][4];
#pragma unroll
  for (int i = 0; i < 4; ++i)
#pragma unroll
    for (int j = 0; j < 4; ++j) acc[i][j] = (floatx4){0.f, 0.f, 0.f, 0.f};

  for (int k = 0; k < K; k += 32) {
    gld_lds16(ag + k, la);
    gld_lds16(ag + half + k, la + 64 * 32);
    gld_lds16(bg + k, lb);
    gld_lds16(bg + half + k, lb + 64 * 32);
    __syncthreads();

    bf16x8 af[4], bf[4];
#pragma unroll
    for (int mt = 0; mt < 4; ++mt)
      af[mt] = *(const bf16x8*)(lds_a + (wm * 64 + mt * 16 + l16) * 32 + quad * 8);
#pragma unroll
    for (int nt = 0; nt < 4; ++nt)
      bf[nt] = *(const bf16x8*)(lds_b + (wn * 64 + nt * 16 + l16) * 32 + quad * 8);
#pragma unroll
    for (int mt = 0; mt < 4; ++mt)
#pragma unroll
      for (int nt = 0; nt < 4; ++nt)
        acc[mt][nt] = __builtin_amdgcn_mfma_f32_16x16x32_bf16(af[mt], bf[nt], acc[mt][nt], 0, 0, 0);
    __syncthreads();
  }

#pragma unroll
  for (int mt = 0; mt < 4; ++mt)
#pragma unroll
    for (int nt = 0; nt < 4; ++nt)
#pragma unroll
      for (int r = 0; r < 4; ++r) {
        size_t row = (size_t)(m0 + wm * 64 + mt * 16 + quad * 4 + r);
        size_t col = (size_t)(n0 + wn * 64 + nt * 16 + l16);
        C[row * Nc + col] = f2bf(acc[mt][nt][r]);
      }
}

// ---------------- split-K 128x128 GEMM, fp32 atomic accumulation ------------
// z = batch*KS + ks; each block computes a K-chunk and atomicAdds into
// Cf [z-batch][M, Nc] fp32 (must be zeroed before launch).
__global__ __launch_bounds__(256) void gemm128_splitk_kernel(
    const short* __restrict__ Ag, const short* __restrict__ Btg,
    float* __restrict__ Cfg, int M, int Nc, int K, int KS,
    long sA, long sB, long sC) {
  __shared__ short lds_a[128 * 32];
  __shared__ short lds_b[128 * 32];
  int tid = threadIdx.x;
  int lane = tid & 63;
  int w = tid >> 6;
  int l16 = lane & 15;
  int quad = lane >> 4;
  int wm = w >> 1, wn = w & 1;
  int m0 = blockIdx.x * 128, n0 = blockIdx.y * 128;
  int bz = blockIdx.z / KS;
  int ks = blockIdx.z % KS;
  int kchunk = K / KS;
  int k0 = ks * kchunk;

  const short* A = Ag + (size_t)bz * sA;
  const short* Bt = Btg + (size_t)bz * sB;
  float* Cf = Cfg + (size_t)bz * sC;

  int srow = tid >> 2;
  int skcol = (tid & 3) * 8;
  const short* ag = A + (size_t)(m0 + srow) * K + skcol;
  const short* bg = Bt + (size_t)(n0 + srow) * K + skcol;
  short* la = lds_a + tid * 8;
  short* lb = lds_b + tid * 8;
  const size_t half = (size_t)64 * K;

  floatx4 acc[4][4];
#pragma unroll
  for (int i = 0; i < 4; ++i)
#pragma unroll
    for (int j = 0; j < 4; ++j) acc[i][j] = (floatx4){0.f, 0.f, 0.f, 0.f};

  for (int k = k0; k < k0 + kchunk; k += 32) {
    gld_lds16(ag + k, la);
    gld_lds16(ag + half + k, la + 64 * 32);
    gld_lds16(bg + k, lb);
    gld_lds16(bg + half + k, lb + 64 * 32);
    __syncthreads();

    bf16x8 af[4], bf[4];
#pragma unroll
    for (int mt = 0; mt < 4; ++mt)
      af[mt] = *(const bf16x8*)(lds_a + (wm * 64 + mt * 16 + l16) * 32 + quad * 8);
#pragma unroll
    for (int nt = 0; nt < 4; ++nt)
      bf[nt] = *(const bf16x8*)(lds_b + (wn * 64 + nt * 16 + l16) * 32 + quad * 8);
#pragma unroll
    for (int mt = 0; mt < 4; ++mt)
#pragma unroll
      for (int nt = 0; nt < 4; ++nt)
        acc[mt][nt] = __builtin_amdgcn_mfma_f32_16x16x32_bf16(af[mt], bf[nt], acc[mt][nt], 0, 0, 0);
    __syncthreads();
  }

#pragma unroll
  for (int mt = 0; mt < 4; ++mt)
#pragma unroll
    for (int nt = 0; nt < 4; ++nt)
#pragma unroll
      for (int r = 0; r < 4; ++r) {
        size_t row = (size_t)(m0 + wm * 64 + mt * 16 + quad * 4 + r);
        size_t col = (size_t)(n0 + wn * 64 + nt * 16 + l16);
        atomicAdd(&Cf[row * Nc + col], acc[mt][nt][r]);
      }
}

// ---------------- merged k/v projection GEMM ----------------
__global__ __launch_bounds__(256) void gemm_kv_kernel(
    const short* __restrict__ xp, const short* __restrict__ WkT,
    const short* __restrict__ WvT, short* __restrict__ kpb,
    short* __restrict__ vpT) {
  int tid = threadIdx.x;
  int w = tid >> 6;
  int lane = tid & 63;
  int l16 = lane & 15;
  int quad = lane >> 4;
  int m_base = blockIdx.x * 64 + (w >> 1) * 32;  // E dim
  int n_base = blockIdx.y * 64 + (w & 1) * 32;   // D dim
  int b = blockIdx.z;

  const short* Ab = xp + (size_t)b * E_ * D_;
  short* Ck = kpb + (size_t)b * E_ * D_;
  short* Cv = vpT + (size_t)b * D_ * E_;

  floatx4 acck[2][2], accv[2][2];
#pragma unroll
  for (int i = 0; i < 2; ++i)
#pragma unroll
    for (int j = 0; j < 2; ++j) {
      acck[i][j] = (floatx4){0.f, 0.f, 0.f, 0.f};
      accv[i][j] = (floatx4){0.f, 0.f, 0.f, 0.f};
    }

  for (int k = 0; k < D_; k += 32) {
    bf16x8 a[2], bk[2], bv[2];
#pragma unroll
    for (int mt = 0; mt < 2; ++mt)
      a[mt] = *(const bf16x8*)(Ab + (size_t)(m_base + mt * 16 + l16) * D_ + k + quad * 8);
#pragma unroll
    for (int nt = 0; nt < 2; ++nt) {
      size_t off = (size_t)(n_base + nt * 16 + l16) * D_ + k + quad * 8;
      bk[nt] = *(const bf16x8*)(WkT + off);
      bv[nt] = *(const bf16x8*)(WvT + off);
    }
#pragma unroll
    for (int mt = 0; mt < 2; ++mt)
#pragma unroll
      for (int nt = 0; nt < 2; ++nt) {
        acck[mt][nt] = __builtin_amdgcn_mfma_f32_16x16x32_bf16(a[mt], bk[nt], acck[mt][nt], 0, 0, 0);
        accv[mt][nt] = __builtin_amdgcn_mfma_f32_16x16x32_bf16(a[mt], bv[nt], accv[mt][nt], 0, 0, 0);
      }
  }

#pragma unroll
  for (int mt = 0; mt < 2; ++mt)
#pragma unroll
    for (int nt = 0; nt < 2; ++nt)
#pragma unroll
      for (int r = 0; r < 4; ++r) {
        size_t row = (size_t)(m_base + mt * 16 + quad * 4 + r);  // E index
        size_t col = (size_t)(n_base + nt * 16 + l16);           // D index
        Ck[row * D_ + col] = f2bf(acck[mt][nt][r]);
        Cv[col * E_ + row] = f2bf(accv[mt][nt][r]);
      }
}

// ---------------- fused attention v3 (unchanged from round 4) ----------------
__global__ __launch_bounds__(512) void attn_kernel(
    const short* __restrict__ q,    // [B*N, D] bf16
    const short* __restrict__ kp,   // [B, E, D] bf16
    const short* __restrict__ vpT,  // [B, D, E] bf16
    float* __restrict__ out) {      // [B, N, D] fp32
  __shared__ short lds_kp_p[17408];  // kp tile (32768 B) then P (34816 B)
  __shared__ short lds_vp[16384];    // vpT tile

  int tid = threadIdx.x;
  int w = tid >> 6;
  int lane = tid & 63;
  int l16 = lane & 15;
  int quad = lane >> 4;
  int n0 = blockIdx.x * 128;
  int h = blockIdx.y;
  int b = blockIdx.z;

  {
    const short* kpg = kp + (size_t)b * E_ * D_ + h * 64;
    int r0 = tid >> 3;
    int sseg = (tid & 7) ^ (r0 & 7);
#pragma unroll
    for (int j = 0; j < 4; ++j)
      gld_lds16(kpg + (size_t)(r0 + j * 64) * D_ + sseg * 8,
                lds_kp_p + j * 4096 + tid * 8);
  }
  {
    const short* vpg = vpT + (size_t)b * D_ * E_ + (size_t)(h * 64) * E_;
    int s1 = tid & 31;
    int rb = tid >> 5;
    int sseg = (s1 & 24) | ((s1 & 7) ^ (rb & 7));
#pragma unroll
    for (int j = 0; j < 4; ++j)
      gld_lds16(vpg + (size_t)(rb + j * 16) * E_ + sseg * 8,
                lds_vp + j * 4096 + tid * 8);
  }

  const short* qbase = q + ((size_t)(b * N_ + n0 + w * 16 + l16)) * D_ + h * 64;
  bf16x8 qf0 = *(const bf16x8*)(qbase + quad * 8);
  bf16x8 qf1 = *(const bf16x8*)(qbase + 32 + quad * 8);

  __syncthreads();

  floatx4 s[16];
#pragma unroll
  for (int t = 0; t < 16; ++t) s[t] = (floatx4){0.f, 0.f, 0.f, 0.f};

  int sw = l16 & 7;
#pragma unroll
  for (int t = 0; t < 16; ++t) {
    int r = t * 16 + l16;
    const short* rowp = lds_kp_p + r * 64;
    bf16x8 a0 = *(const bf16x8*)(rowp + ((quad) ^ sw) * 8);
    bf16x8 a1 = *(const bf16x8*)(rowp + ((4 + quad) ^ sw) * 8);
    s[t] = __builtin_amdgcn_mfma_f32_16x16x32_bf16(a0, qf0, s[t], 0, 0, 0);
    s[t] = __builtin_amdgcn_mfma_f32_16x16x32_bf16(a1, qf1, s[t], 0, 0, 0);
  }

  float mx = -1e30f;
#pragma unroll
  for (int t = 0; t < 16; ++t)
#pragma unroll
    for (int r = 0; r < 4; ++r) {
      s[t][r] *= 0.125f;
      mx = fmaxf(mx, s[t][r]);
    }
  mx = fmaxf(mx, __shfl_xor(mx, 16, 64));
  mx = fmaxf(mx, __shfl_xor(mx, 32, 64));

  float lsum = 0.f;
#pragma unroll
  for (int t = 0; t < 16; ++t)
#pragma unroll
    for (int r = 0; r < 4; ++r) {
      s[t][r] = __expf(s[t][r] - mx);
      lsum += s[t][r];
    }
  lsum += __shfl_xor(lsum, 16, 64);
  lsum += __shfl_xor(lsum, 32, 64);

  __syncthreads();

  short* pbase = lds_kp_p + w * 2176;
  floatx4 o4[4];
#pragma unroll
  for (int t2 = 0; t2 < 4; ++t2) o4[t2] = (floatx4){0.f, 0.f, 0.f, 0.f};

#pragma unroll
  for (int hf = 0; hf < 2; ++hf) {
#pragma unroll
    for (int t = 0; t < 8; ++t)
#pragma unroll
      for (int r = 0; r < 4; ++r)
        pbase[l16 * 136 + t * 16 + quad * 4 + r] = f2bf(s[hf * 8 + t][r]);

#pragma unroll
    for (int es2 = 0; es2 < 4; ++es2) {
      bf16x8 pa = *(const bf16x8*)(pbase + l16 * 136 + es2 * 32 + quad * 8);
      int es = hf * 4 + es2;
#pragma unroll
      for (int t2 = 0; t2 < 4; ++t2) {
        int rr = t2 * 16 + l16;
        int seg = es * 4 + quad;
        int sg = (seg & 24) | ((seg & 7) ^ sw);
        bf16x8 vf = *(const bf16x8*)(lds_vp + rr * 256 + sg * 8);
        o4[t2] = __builtin_amdgcn_mfma_f32_16x16x32_bf16(pa, vf, o4[t2], 0, 0, 0);
      }
    }
  }

  float linv[4];
#pragma unroll
  for (int r = 0; r < 4; ++r)
    linv[r] = 1.0f / __shfl(lsum, (lane & 48) | (quad * 4 + r), 64);

#pragma unroll
  for (int r = 0; r < 4; ++r) {
    int n = n0 + w * 16 + quad * 4 + r;
#pragma unroll
    for (int t2 = 0; t2 < 4; ++t2)
      out[((size_t)(b * N_ + n)) * D_ + h * 64 + t2 * 16 + l16] = o4[t2][r] * linv[r];
  }
}

extern "C" void kernel_launch(void* const* d_in, const int* in_sizes, int n_in,
                              void* d_out, int out_size, void* d_ws, size_t ws_size,
                              hipStream_t stream) {
  const float* x    = (const float*)d_in[0];  // [B,N,D]
  const float* proj = (const float*)d_in[1];  // [N,E]
  const float* Wq   = (const float*)d_in[2];  // [D,D]
  const float* Wk   = (const float*)d_in[3];
  const float* Wv   = (const float*)d_in[4];
  float* out = (float*)d_out;

  short* p = (short*)d_ws;
  short* xtb_qb = p; p += (size_t)B_ * D_ * N_;  // xtb, later qb
  short* xb     = p; p += (size_t)B_ * N_ * D_;
  short* WqT    = p; p += (size_t)D_ * D_;
  short* WkT    = p; p += (size_t)D_ * D_;
  short* WvT    = p; p += (size_t)D_ * D_;
  short* projT  = p; p += (size_t)E_ * N_;
  short* xp     = p; p += (size_t)B_ * E_ * D_;
  short* kpb    = p; p += (size_t)B_ * E_ * D_;
  short* vpT    = p; p += (size_t)B_ * D_ * E_;
  float* xp_f32 = (float*)p;                     // B*E*D fp32 = 4 MB
  short* xtb = xtb_qb;
  short* qb  = xtb_qb;

  dim3 blkT(32, 8);
  transpose_x_kernel<<<dim3(D_ / 32, N_ / 32, B_), blkT, 0, stream>>>(x, xtb, xb);
  transpose_w_kernel<<<dim3(D_ / 32, D_ / 32, 3), blkT, 0, stream>>>(Wq, Wk, Wv, WqT, WkT, WvT);
  transpose_p_kernel<<<dim3(E_ / 32, N_ / 32, 1), blkT, 0, stream>>>(proj, projT);

  // xp[b] = proj^T @ x[b] — split-K (KS=8 -> 512 blocks) + fp32 atomics
  hipMemsetAsync(xp_f32, 0, (size_t)B_ * E_ * D_ * sizeof(float), stream);
  const int KS = 8;
  gemm128_splitk_kernel<<<dim3(E_ / 128, D_ / 128, B_ * KS), 256, 0, stream>>>(
      projT, xtb, xp_f32, E_, D_, N_, KS, 0, (long)D_ * N_, (long)E_ * D_);
  cast_f32_bf16_kernel<<<(B_ * E_ * D_) / 1024, 256, 0, stream>>>(xp_f32, xp);

  // q = xb @ W_q  (128-tile; qb overwrites dead xtb)
  gemm128_bt_kernel<<<dim3((B_ * N_) / 128, D_ / 128, 1), 256, 0, stream>>>(
      xb, WqT, qb, B_ * N_, D_, D_, 0, 0, 0);

  // k_proj / v_proj^T fused (shared A-fragments)
  gemm_kv_kernel<<<dim3(E_ / 64, D_ / 64, B_), 256, 0, stream>>>(
      xp, WkT, WvT, kpb, vpT);

  attn_kernel<<<dim3(N_ / 128, H_, B_), 512, 0, stream>>>(qb, kpb, vpT, out);
}